// Round 2
// baseline (34888.977 us; speedup 1.0000x reference)
//
#include <hip/hip_runtime.h>
#include <hip/hip_bf16.h>

// Problem constants
#define BB 128   // batch
#define TT 1024  // timesteps
#define HH 512   // hidden
#define VV 256   // vocab

typedef __attribute__((ext_vector_type(8))) short short8;   // 8 x bf16 (4 VGPRs)
typedef __attribute__((ext_vector_type(4))) float floatx4;  // MFMA accumulator

__device__ __forceinline__ floatx4 mfma16(short8 a, short8 b, floatx4 c) {
    return __builtin_amdgcn_mfma_f32_16x16x32_bf16(a, b, c, 0, 0, 0);
}
__device__ __forceinline__ float sigm(float x) { return 1.0f / (1.0f + __expf(-x)); }
__device__ __forceinline__ float tanh_fast(float x) {
    return 2.0f / (1.0f + __expf(-2.0f * x)) - 1.0f;   // saturates correctly
}

// One-shot canonicalization: fp32 weights -> bf16 copies in ws; bias pre-sums in fp32.
__global__ __launch_bounds__(256) void canon(
    const float* __restrict__ Whh1, const float* __restrict__ Wih2,
    const float* __restrict__ Whh2, const float* __restrict__ Wlin,
    const float* __restrict__ bih1, const float* __restrict__ bhh1,
    const float* __restrict__ bih2, const float* __restrict__ bhh2,
    __hip_bfloat16* __restrict__ Whh1c, __hip_bfloat16* __restrict__ Wih2c,
    __hip_bfloat16* __restrict__ Whh2c, __hip_bfloat16* __restrict__ Wlinc,
    float* __restrict__ bsum1, float* __restrict__ bsum2)
{
    const int tid = blockIdx.x * blockDim.x + threadIdx.x;
    const int np  = gridDim.x * blockDim.x;
    for (int i = tid; i < 2048 * 512; i += np) {
        Whh1c[i] = __float2bfloat16(Whh1[i]);
        Wih2c[i] = __float2bfloat16(Wih2[i]);
        Whh2c[i] = __float2bfloat16(Whh2[i]);
    }
    for (int i = tid; i < 256 * 512; i += np) Wlinc[i] = __float2bfloat16(Wlin[i]);
    for (int i = tid; i < 2048; i += np) {
        bsum1[i] = bih1[i] + bhh1[i];
        bsum2[i] = bih2[i] + bhh2[i];
    }
}

// Pipelined step kernel, launch s in [0, TT+1]:
//   blocks [0,64)    : layer1 @ t  = s       (s < TT)
//   blocks [64,128)  : layer2 @ t2 = s-1     (1 <= s <= TT)
//   blocks [128,130) : linear+softmax @ t3 = s-2  (2 <= s <= TT+1)
// Buffer parities:
//   h1buf: written parity s&1 by stage1; stage1/stage2 read parity (s+1)&1 (= state after s-1)
//   h2buf: written parity (s+1)&1 by stage2 (state after s-1);
//          stage2+stage3 read parity s&1 (= state after s-2 = h2(t3))
__global__ __launch_bounds__(256) void lstm_step(
    const float* __restrict__ x,               // [B, T] fp32
    const float* __restrict__ Wih1,            // [2048] fp32 (IN=1)
    const __hip_bfloat16* __restrict__ Whh1c,  // [2048, 512] bf16
    const float* __restrict__ bsum1,           // [2048] fp32
    const __hip_bfloat16* __restrict__ Wih2c,  // [2048, 512] bf16
    const __hip_bfloat16* __restrict__ Whh2c,  // [2048, 512] bf16
    const float* __restrict__ bsum2,           // [2048] fp32
    const __hip_bfloat16* __restrict__ Wlinc,  // [256, 512] bf16
    const float* __restrict__ blin,            // [256] fp32
    __hip_bfloat16* __restrict__ h1buf,        // [2][B*H] bf16
    __hip_bfloat16* __restrict__ h2buf,        // [2][B*H] bf16
    float* __restrict__ c1,                    // [B*H] fp32
    float* __restrict__ c2,                    // [B*H] fp32
    float* __restrict__ out,                   // [B, T, V] fp32
    int s)
{
    const int bid  = blockIdx.x;
    const int w    = threadIdx.x >> 6;
    const int lane = threadIdx.x & 63;
    const int q    = lane >> 4;
    const int ln   = lane & 15;
    const size_t BH = (size_t)BB * HH;

    if (bid < 128) {
        const int layer = bid >> 6;
        if (layer == 0 && s >= TT) return;
        if (layer == 1 && (s < 1 || s > TT)) return;

        const int lb = bid & 63;
        const int j0 = (lb & 31) * 16;           // h-unit tile
        const int b0 = (lb >> 5) * 64;           // batch tile
        const int r0 = b0 + w * 16;              // wave's 16 batch rows

        const __hip_bfloat16* hA = h1buf + (size_t)((s + 1) & 1) * BH;  // h1 after s-1
        const int arow = (r0 + ln) * HH + q * 8; // A[m=ln][k=q*8+j]

        floatx4 acc[4];
        #pragma unroll
        for (int g = 0; g < 4; ++g) acc[g] = floatx4{0, 0, 0, 0};

        if (layer == 0) {
            // gates = h1_prev @ Whh1^T (x / bias in epilogue, exact fp32)
            #pragma unroll
            for (int kk = 0; kk < 16; ++kk) {
                short8 a = *(const short8*)(hA + arow + kk * 32);
                #pragma unroll
                for (int g = 0; g < 4; ++g) {
                    const int n = g * 512 + j0 + ln;
                    short8 bf = *(const short8*)(Whh1c + n * HH + kk * 32 + q * 8);
                    acc[g] = mfma16(a, bf, acc[g]);
                }
            }
            const int t = s;
            #pragma unroll
            for (int reg = 0; reg < 4; ++reg) {
                const int b = r0 + q * 4 + reg;      // C/D row
                const int j = j0 + ln;               // C/D col
                const float xv = x[b * TT + t];
                float gi = acc[0][reg] + xv * Wih1[       j] + bsum1[       j];
                float gf = acc[1][reg] + xv * Wih1[ 512 + j] + bsum1[ 512 + j];
                float gg = acc[2][reg] + xv * Wih1[1024 + j] + bsum1[1024 + j];
                float go = acc[3][reg] + xv * Wih1[1536 + j] + bsum1[1536 + j];
                const int idx = b * HH + j;
                float cnew = sigm(gf) * c1[idx] + sigm(gi) * tanh_fast(gg);
                c1[idx] = cnew;
                float hnew = sigm(go) * tanh_fast(cnew);
                h1buf[(size_t)(s & 1) * BH + idx] = __float2bfloat16(hnew);
            }
        } else {
            // layer2 @ t2 = s-1: gates = h1(t2) @ Wih2^T + h2(t2-1) @ Whh2^T
            const __hip_bfloat16* hB = h2buf + (size_t)(s & 1) * BH;  // h2 after s-2
            #pragma unroll
            for (int kk = 0; kk < 16; ++kk) {
                short8 a = *(const short8*)(hA + arow + kk * 32);
                #pragma unroll
                for (int g = 0; g < 4; ++g) {
                    const int n = g * 512 + j0 + ln;
                    short8 bf = *(const short8*)(Wih2c + n * HH + kk * 32 + q * 8);
                    acc[g] = mfma16(a, bf, acc[g]);
                }
            }
            #pragma unroll
            for (int kk = 0; kk < 16; ++kk) {
                short8 a = *(const short8*)(hB + arow + kk * 32);
                #pragma unroll
                for (int g = 0; g < 4; ++g) {
                    const int n = g * 512 + j0 + ln;
                    short8 bf = *(const short8*)(Whh2c + n * HH + kk * 32 + q * 8);
                    acc[g] = mfma16(a, bf, acc[g]);
                }
            }
            #pragma unroll
            for (int reg = 0; reg < 4; ++reg) {
                const int b = r0 + q * 4 + reg;
                const int j = j0 + ln;
                float gi = acc[0][reg] + bsum2[       j];
                float gf = acc[1][reg] + bsum2[ 512 + j];
                float gg = acc[2][reg] + bsum2[1024 + j];
                float go = acc[3][reg] + bsum2[1536 + j];
                const int idx = b * HH + j;
                float cnew = sigm(gf) * c2[idx] + sigm(gi) * tanh_fast(gg);
                c2[idx] = cnew;
                float hnew = sigm(go) * tanh_fast(cnew);
                h2buf[(size_t)((s + 1) & 1) * BH + idx] = __float2bfloat16(hnew);
            }
        }
    } else {
        // stage3: linear + softmax @ t3 = s-2 (reads h2 parity s&1 = h2(t3))
        if (s < 2) return;
        const int t3 = s - 2;
        const __hip_bfloat16* hC = h2buf + (size_t)(s & 1) * BH;
        const int r0 = (bid - 128) * 64 + w * 16;     // batch rows

        floatx4 acc[16];
        #pragma unroll
        for (int n = 0; n < 16; ++n) acc[n] = floatx4{0, 0, 0, 0};

        const int arow = (r0 + ln) * HH + q * 8;
        #pragma unroll 4
        for (int kk = 0; kk < 16; ++kk) {
            short8 a = *(const short8*)(hC + arow + kk * 32);
            #pragma unroll
            for (int n = 0; n < 16; ++n) {
                short8 bf = *(const short8*)(Wlinc + (n * 16 + ln) * HH + kk * 32 + q * 8);
                acc[n] = mfma16(a, bf, acc[n]);
            }
        }

        float bl[16];
        #pragma unroll
        for (int n = 0; n < 16; ++n) bl[n] = blin[n * 16 + ln];

        #pragma unroll
        for (int reg = 0; reg < 4; ++reg) {
            float v[16];
            float mx = -3.4e38f;
            #pragma unroll
            for (int n = 0; n < 16; ++n) {
                v[n] = acc[n][reg] + bl[n];
                mx = fmaxf(mx, v[n]);
            }
            #pragma unroll
            for (int m = 1; m < 16; m <<= 1) mx = fmaxf(mx, __shfl_xor(mx, m));
            float sum = 0.0f;
            #pragma unroll
            for (int n = 0; n < 16; ++n) { v[n] = __expf(v[n] - mx); sum += v[n]; }
            #pragma unroll
            for (int m = 1; m < 16; m <<= 1) sum += __shfl_xor(sum, m);
            const float inv = 1.0f / sum;

            const int b = r0 + q * 4 + reg;
            float* orow = out + ((size_t)b * TT + t3) * VV;
            #pragma unroll
            for (int n = 0; n < 16; ++n)
                orow[n * 16 + ln] = v[n] * inv;
        }
    }
}

extern "C" void kernel_launch(void* const* d_in, const int* in_sizes, int n_in,
                              void* d_out, int out_size, void* d_ws, size_t ws_size,
                              hipStream_t stream)
{
    const float* x     = (const float*)d_in[0];
    const float* W_ih1 = (const float*)d_in[1];
    const float* W_hh1 = (const float*)d_in[2];
    const float* b_ih1 = (const float*)d_in[3];
    const float* b_hh1 = (const float*)d_in[4];
    const float* W_ih2 = (const float*)d_in[5];
    const float* W_hh2 = (const float*)d_in[6];
    const float* b_ih2 = (const float*)d_in[7];
    const float* b_hh2 = (const float*)d_in[8];
    const float* W_lin = (const float*)d_in[9];
    const float* b_lin = (const float*)d_in[10];

    char* ws = (char*)d_ws;
    const size_t BH = (size_t)BB * HH;
    float* c1 = (float*)ws;                                     // 256 KB
    float* c2 = (float*)(ws + BH * 4);                          // 256 KB
    __hip_bfloat16* h1buf = (__hip_bfloat16*)(ws + 2 * BH * 4);             // 256 KB (2 bufs)
    __hip_bfloat16* h2buf = (__hip_bfloat16*)(ws + 2 * BH * 4 + 2 * BH * 2);// 256 KB (2 bufs)
    const size_t state_bytes = 2 * BH * 4 + 4 * BH * 2;         // 1 MiB
    char* p = ws + state_bytes;
    float* bsum1 = (float*)p;            p += 2048 * 4;
    float* bsum2 = (float*)p;            p += 2048 * 4;
    __hip_bfloat16* Whh1c = (__hip_bfloat16*)p; p += (size_t)2048 * 512 * 2;
    __hip_bfloat16* Wih2c = (__hip_bfloat16*)p; p += (size_t)2048 * 512 * 2;
    __hip_bfloat16* Whh2c = (__hip_bfloat16*)p; p += (size_t)2048 * 512 * 2;
    __hip_bfloat16* Wlinc = (__hip_bfloat16*)p; p += (size_t)256 * 512 * 2;
    // total ws use ~7.6 MB

    // zero initial h/c state (ws is poisoned 0xAA before every launch)
    hipMemsetAsync(d_ws, 0, state_bytes, stream);

    // canonicalize weights (fp32 -> bf16) + bias pre-sums
    canon<<<dim3(304), dim3(256), 0, stream>>>(
        W_hh1, W_ih2, W_hh2, W_lin, b_ih1, b_hh1, b_ih2, b_hh2,
        Whh1c, Wih2c, Whh2c, Wlinc, bsum1, bsum2);

    // pipelined recurrence: launch s does layer1(s) || layer2(s-1) || lin+softmax(s-2)
    for (int s = 0; s <= TT + 1; ++s) {
        lstm_step<<<dim3(130), dim3(256), 0, stream>>>(
            x, W_ih1, Whh1c, bsum1, Wih2c, Whh2c, bsum2, Wlinc, b_lin,
            h1buf, h2buf, c1, c2, (float*)d_out, s);
    }
}